// Round 7
// baseline (3003.091 us; speedup 1.0000x reference)
//
#include <hip/hip_runtime.h>

// Problem constants
#define TDEC 50
#define NB   32
#define NPTS 512
#define DEMB 512
#define DENC 1024
#define DDEC 1024
#define G4   4096
#define NEGBIG 1e20f
#define NBLK_LSTM 512

__device__ __forceinline__ float sigf(float x) {
  float e = __expf(-fabsf(x));
  float r = 1.0f / (1.0f + e);
  return x >= 0.0f ? r : 1.0f - r;
}
__device__ __forceinline__ float tanh_(float x) {
  return 2.0f * sigf(2.0f * x) - 1.0f;
}
__device__ __forceinline__ unsigned short f2b(float f) {
  union { float f; unsigned int u; } v; v.f = f;
  unsigned int r = v.u + 0x7FFFu + ((v.u >> 16) & 1u);   // RNE
  return (unsigned short)(r >> 16);
}
__device__ __forceinline__ float b2f(unsigned short u) {
  union { unsigned int i; float f; } v; v.i = ((unsigned int)u) << 16;
  return v.f;
}

using bf16x8_t = __attribute__((ext_vector_type(8))) __bf16;
using u16x8    = __attribute__((ext_vector_type(8))) unsigned short;
using f32x4    = __attribute__((ext_vector_type(4))) float;

// ---------------- prep kernels ----------------

__global__ void k_zero(unsigned* __restrict__ bar) {
  if (threadIdx.x < 2) bar[threadIdx.x] = 0u;
}

__global__ void k_first(const int* __restrict__ gt, int* __restrict__ ft) {
  int idx = blockIdx.x * blockDim.x + threadIdx.x;
  if (idx >= NB * NPTS) return;
  int b = idx >> 9, n = idx & (NPTS - 1);
  int first = TDEC;
  for (int t = 0; t < TDEC; ++t) {
    int g = gt[b * TDEC + t];
    if (g == n && t < first) first = t;
  }
  ft[idx] = first;
}

__global__ void k_gather(const float* __restrict__ emb, const int* __restrict__ gt,
                         const float* __restrict__ go, float* __restrict__ Xin) {
  int idx = blockIdx.x * blockDim.x + threadIdx.x;
  if (idx >= TDEC * NB * DEMB) return;
  int d = idx & (DEMB - 1);
  int tb = idx >> 9;
  int b = tb & (NB - 1);
  int t = tb >> 5;
  float v;
  if (t == 0) v = go[d];
  else {
    int g = gt[b * TDEC + (t - 1)];
    v = emb[((long long)b * NPTS + g) * DEMB + d];
  }
  Xin[idx] = v;
}

// fp32 -> bf16 elementwise (n8 = count/8)
__global__ void k_cvt8(const float* __restrict__ s, unsigned short* __restrict__ d, int n8) {
  int idx = blockIdx.x * blockDim.x + threadIdx.x;
  if (idx >= n8) return;
  float4 a = *(const float4*)(s + (long long)idx * 8);
  float4 b = *(const float4*)(s + (long long)idx * 8 + 4);
  u16x8 o;
  o[0]=f2b(a.x); o[1]=f2b(a.y); o[2]=f2b(a.z); o[3]=f2b(a.w);
  o[4]=f2b(b.x); o[5]=f2b(b.y); o[6]=f2b(b.z); o[7]=f2b(b.w);
  *(u16x8*)(d + (long long)idx * 8) = o;
}

// H[r][1024] fp32 -> HAcat[r][0..1023] bf16 (row stride 2048)
__global__ void k_cvtH(const float* __restrict__ H, unsigned short* __restrict__ HAcat, int n8) {
  int idx = blockIdx.x * blockDim.x + threadIdx.x;
  if (idx >= n8) return;
  int r = idx >> 7, c = (idx & 127) << 3;
  float4 a = *(const float4*)(H + (long long)r * 1024 + c);
  float4 b = *(const float4*)(H + (long long)r * 1024 + c + 4);
  u16x8 o;
  o[0]=f2b(a.x); o[1]=f2b(a.y); o[2]=f2b(a.z); o[3]=f2b(a.w);
  o[4]=f2b(b.x); o[5]=f2b(b.y); o[6]=f2b(b.z); o[7]=f2b(b.w);
  *(u16x8*)(HAcat + (long long)r * 2048 + c) = o;
}

// enc[b][n][e] f32 -> encT[b][e][n] bf16
__global__ __launch_bounds__(256) void k_transposeEnc(const float* __restrict__ enc,
                                                      unsigned short* __restrict__ encT) {
  __shared__ float tile[64][65];
  int n0 = blockIdx.x * 64, e0 = blockIdx.y * 64, b = blockIdx.z;
  const float* E = enc + (long long)b * 512 * DENC;
  unsigned short* ET = encT + (long long)b * DENC * 512;
  int tid = threadIdx.x;
  int nr = tid >> 2, q = tid & 3;
#pragma unroll
  for (int i = 0; i < 4; ++i) {
    float4 v = *(const float4*)(E + (long long)(n0 + nr) * DENC + e0 + q * 16 + i * 4);
    tile[nr][q * 16 + i * 4 + 0] = v.x; tile[nr][q * 16 + i * 4 + 1] = v.y;
    tile[nr][q * 16 + i * 4 + 2] = v.z; tile[nr][q * 16 + i * 4 + 3] = v.w;
  }
  __syncthreads();
  int er = tid >> 2;
#pragma unroll
  for (int i = 0; i < 4; ++i) {
    ushort4 o;
    o.x = f2b(tile[q * 16 + i * 4 + 0][er]); o.y = f2b(tile[q * 16 + i * 4 + 1][er]);
    o.z = f2b(tile[q * 16 + i * 4 + 2][er]); o.w = f2b(tile[q * 16 + i * 4 + 3][er]);
    *(ushort4*)(ET + (long long)(e0 + er) * 512 + n0 + q * 16 + i * 4) = o;
  }
}

// ---------------- fp32 tiled GEMM (TN), with optional K-chunking ----------------
struct GemmP {
  const float* A; long long aBatch; int lda;
  const float* B; long long bBatch; int ldb;
  float* C; long long cBatch; long long ldcM; long long ldcN;
  int M, N, K;
  const float* bias1; const float* bias2;
  int kcN; long long kcStride;
};

__global__ __launch_bounds__(256) void k_gemm(GemmP p) {
  __shared__ float As[16][68];
  __shared__ float Bs[16][68];
  const int zb = blockIdx.z / p.kcN;
  const int kc = blockIdx.z % p.kcN;
  const float* A = p.A + (long long)zb * p.aBatch;
  const float* B = p.B + (long long)zb * p.bBatch;
  const int m0 = blockIdx.x * 64, n0 = blockIdx.y * 64;
  const int tid = threadIdx.x;
  const int lm = tid >> 2;
  const int lk = (tid & 3) << 2;
  const int tm = tid & 15, tn = tid >> 4;
  const int kChunk = p.K / p.kcN;
  const int kLo = kc * kChunk, kHi = kLo + kChunk;
  float acc[4][4] = {};
  for (int k0 = kLo; k0 < kHi; k0 += 16) {
    float4 av = make_float4(0.f, 0.f, 0.f, 0.f);
    float4 bv = make_float4(0.f, 0.f, 0.f, 0.f);
    {
      int am = m0 + lm, kk = k0 + lk;
      if (am < p.M) av = *(const float4*)(A + (long long)am * p.lda + kk);
    }
    {
      int bn = n0 + lm, kk = k0 + lk;
      if (bn < p.N) bv = *(const float4*)(B + (long long)bn * p.ldb + kk);
    }
    __syncthreads();
    As[lk + 0][lm] = av.x; As[lk + 1][lm] = av.y;
    As[lk + 2][lm] = av.z; As[lk + 3][lm] = av.w;
    Bs[lk + 0][lm] = bv.x; Bs[lk + 1][lm] = bv.y;
    Bs[lk + 2][lm] = bv.z; Bs[lk + 3][lm] = bv.w;
    __syncthreads();
#pragma unroll
    for (int kk = 0; kk < 16; ++kk) {
      float4 a = *(const float4*)&As[kk][tm << 2];
      float4 b = *(const float4*)&Bs[kk][tn << 2];
      float ar[4] = {a.x, a.y, a.z, a.w};
      float br[4] = {b.x, b.y, b.z, b.w};
#pragma unroll
      for (int i = 0; i < 4; ++i)
#pragma unroll
        for (int j = 0; j < 4; ++j) acc[i][j] += ar[i] * br[j];
    }
  }
  float* C = p.C + (long long)zb * p.cBatch + (long long)kc * p.kcStride;
#pragma unroll
  for (int i = 0; i < 4; ++i) {
    int m = m0 + (tm << 2) + i;
    if (m >= p.M) continue;
#pragma unroll
    for (int j = 0; j < 4; ++j) {
      int n = n0 + (tn << 2) + j;
      if (n >= p.N) continue;
      float v = acc[i][j];
      if (p.bias1) v += p.bias1[n];
      if (p.bias2) v += p.bias2[n];
      C[(long long)m * p.ldcM + (long long)n * p.ldcN] = v;
    }
  }
}

// ---------------- bf16 MFMA GEMM (TN: C = A * B^T), 64x64 tile, BK=32 ----------------
struct GemmBP {
  const unsigned short* A; long long aBatch; int lda;
  const unsigned short* B; long long bBatch; int ldb;
  void* C; long long cBatch; long long ldcM; long long ldcN;
  int M, N, K;
  const float* bias;
  const int* ft; const float* emb_mask;
};

template <int MODE>
__global__ __launch_bounds__(256) void k_bgemm(GemmBP p) {
  __shared__ unsigned short As[64][40];
  __shared__ unsigned short Bs[64][40];
  const int z = blockIdx.z;
  const unsigned short* A = p.A + (long long)z * p.aBatch;
  const unsigned short* B = p.B + (long long)z * p.bBatch;
  const int m0 = blockIdx.x * 64, n0 = blockIdx.y * 64;
  const int tid = threadIdx.x;
  const int srow = tid >> 2, skq = tid & 3;
  const int lane = tid & 63, wave = tid >> 6;
  const int wm = (wave >> 1) * 32, wn = (wave & 1) * 32;
  const int lr = lane & 15, lk = (lane >> 4) * 8;
  f32x4 acc[2][2] = {};
  for (int k0 = 0; k0 < p.K; k0 += 32) {
    u16x8 av = {}, bv = {};
    int gm = m0 + srow;
    if (gm < p.M) av = *(const u16x8*)(A + (long long)gm * p.lda + k0 + skq * 8);
    int gn = n0 + srow;
    if (gn < p.N) bv = *(const u16x8*)(B + (long long)gn * p.ldb + k0 + skq * 8);
    __syncthreads();
    *(u16x8*)&As[srow][skq * 8] = av;
    *(u16x8*)&Bs[srow][skq * 8] = bv;
    __syncthreads();
#pragma unroll
    for (int mi = 0; mi < 2; ++mi) {
      bf16x8_t af = *(const bf16x8_t*)&As[wm + mi * 16 + lr][lk];
#pragma unroll
      for (int ni = 0; ni < 2; ++ni) {
        bf16x8_t bfv = *(const bf16x8_t*)&Bs[wn + ni * 16 + lr][lk];
        acc[mi][ni] = __builtin_amdgcn_mfma_f32_16x16x32_bf16(af, bfv, acc[mi][ni], 0, 0, 0);
      }
    }
  }
  const int rbase = (lane >> 4) * 4, cOff = lane & 15;
#pragma unroll
  for (int mi = 0; mi < 2; ++mi)
#pragma unroll
    for (int ni = 0; ni < 2; ++ni)
#pragma unroll
      for (int r = 0; r < 4; ++r) {
        int m = m0 + wm + mi * 16 + rbase + r;
        int n = n0 + wn + ni * 16 + cOff;
        if (m >= p.M || n >= p.N) continue;
        float v = acc[mi][ni][r];
        if (MODE == 0) {
          if (p.bias) v += p.bias[n];
          ((unsigned short*)p.C)[(long long)z * p.cBatch + (long long)m * p.ldcM +
                                 (long long)n * p.ldcN] = f2b(v);
        } else {
          float fl = b2f(B[(long long)n * p.ldb + DEMB]);
          if (p.ft[z * NPTS + m] < n) v += fl;
          v -= (1.0f - p.emb_mask[z * NPTS + m]) * NEGBIG;
          ((float*)p.C)[(long long)z * p.cBatch + (long long)m * p.ldcM +
                        (long long)n * p.ldcN] = v;
        }
      }
}

// ---------------- persistent LSTM: one kernel, 50 steps, grid barrier ----------------
// 512 blocks x 256 threads (2 blocks/CU, co-resident). Block bid owns hidden units
// {bid*2, bid*2+1}: stages the 8 corresponding W_hh rows (i,f,g,o x 2 units) in LDS.
// Per step: matvec vs h_{t-1} (global, 8-lane-broadcast float4 reads), add XW pre-gates,
// local cell update (c stays in LDS), write 64 h values to H[t], device-wide barrier.
__global__ __launch_bounds__(256, 2) void k_lstm_persist(
    const float* __restrict__ W_hh, const float* __restrict__ XW,
    float* __restrict__ H, unsigned* bar) {
  __shared__ float Wl[8][1028];   // pad: (r*1028+k)%32 = (r*4+k)%32 -> conflict-free
  __shared__ float gbuf[8][33];
  __shared__ float cst[2][32];
  const int bid = blockIdx.x;
  const int tid = threadIdx.x;
  // stage 8 W_hh rows: r -> j = (r>>1)*1024 + bid*2 + (r&1)
  for (int i = tid; i < 8 * 256; i += 256) {
    int r = i >> 8, kq = (i & 255) << 2;
    int j = (r >> 1) * 1024 + bid * 2 + (r & 1);
    float4 v = *(const float4*)(W_hh + (long long)j * 1024 + kq);
    Wl[r][kq + 0] = v.x; Wl[r][kq + 1] = v.y; Wl[r][kq + 2] = v.z; Wl[r][kq + 3] = v.w;
  }
  const int r = tid & 7, b = tid >> 3;
  const int j = (r >> 1) * 1024 + bid * 2 + (r & 1);
  __syncthreads();
  for (int t = 0; t < TDEC; ++t) {
    float acc = 0.f;
    if (t > 0) {
      const float* hp = H + ((long long)(t - 1) * NB + b) * DDEC;
#pragma unroll 4
      for (int k = 0; k < DDEC; k += 4) {
        float4 h4 = *(const float4*)(hp + k);
        float4 w4 = *(const float4*)&Wl[r][k];
        acc += w4.x * h4.x + w4.y * h4.y + w4.z * h4.z + w4.w * h4.w;
      }
    }
    acc += XW[((long long)t * NB + b) * G4 + j];
    gbuf[r][b] = acc;
    __syncthreads();
    if (tid < 64) {
      int ul = tid >> 5, bb = tid & 31;
      float gi = gbuf[0 + ul][bb], gf = gbuf[2 + ul][bb];
      float gg = gbuf[4 + ul][bb], go_ = gbuf[6 + ul][bb];
      float cp = (t == 0) ? 0.f : cst[ul][bb];
      float cv = sigf(gf) * cp + sigf(gi) * tanh_(gg);
      cst[ul][bb] = cv;
      float hv = sigf(go_) * tanh_(cv);
      H[((long long)t * NB + bb) * DDEC + bid * 2 + ul] = hv;
    }
    __syncthreads();               // block's stores issued & drained (vmcnt at barrier)
    if (tid == 0) {
      __threadfence();             // release: flush to device coherence point (cross-XCD)
      unsigned my = __hip_atomic_fetch_add(&bar[0], 1u, __ATOMIC_RELAXED,
                                           __HIP_MEMORY_SCOPE_AGENT) + 1u;
      unsigned target = (unsigned)(t + 1) * NBLK_LSTM;
      if (my == target) {
        __hip_atomic_store(&bar[1], (unsigned)(t + 1), __ATOMIC_RELEASE,
                           __HIP_MEMORY_SCOPE_AGENT);
      } else {
        while (__hip_atomic_load(&bar[1], __ATOMIC_RELAXED,
                                 __HIP_MEMORY_SCOPE_AGENT) < (unsigned)(t + 1)) {
          __builtin_amdgcn_s_sleep(2);
        }
      }
      __threadfence();             // acquire: invalidate L1/L2 before reading fresh H
    }
    __syncthreads();
  }
}

// ---------------- masked softmax over 512, sums 2 K-chunks, emits bf16 p ----------------
__global__ __launch_bounds__(256) void k_softmax(const float* __restrict__ praw,
                                                 unsigned short* __restrict__ p_bf,
                                                 const float* __restrict__ enc_mask) {
  __shared__ float red[8];
  __shared__ float red2[8];
  const long long kcStride = (long long)NB * TDEC * 512;
  int bt = blockIdx.x;
  int b = bt / TDEC;
  const float* r0 = praw + (long long)bt * 512;
  const float* r1 = r0 + kcStride;
  int tid = threadIdx.x;
  float v0 = r0[tid] + r1[tid] - (1.0f - enc_mask[b * 512 + tid]) * NEGBIG;
  float v1 = r0[tid + 256] + r1[tid + 256] - (1.0f - enc_mask[b * 512 + tid + 256]) * NEGBIG;
  float mx = fmaxf(v0, v1);
  for (int off = 32; off; off >>= 1) mx = fmaxf(mx, __shfl_xor(mx, off));
  if ((tid & 63) == 0) red[tid >> 6] = mx;
  __syncthreads();
  mx = fmaxf(fmaxf(red[0], red[1]), fmaxf(red[2], red[3]));
  float e0 = __expf(v0 - mx), e1 = __expf(v1 - mx);
  float s = e0 + e1;
  for (int off = 32; off; off >>= 1) s += __shfl_xor(s, off);
  if ((tid & 63) == 0) red2[tid >> 6] = s;
  __syncthreads();
  s = red2[0] + red2[1] + red2[2] + red2[3];
  float inv = 1.0f / s;
  p_bf[(long long)bt * 512 + tid] = f2b(e0 * inv);
  p_bf[(long long)bt * 512 + tid + 256] = f2b(e1 * inv);
}

// ---------------- host launcher ----------------
extern "C" void kernel_launch(void* const* d_in, const int* in_sizes, int n_in,
                              void* d_out, int out_size, void* d_ws, size_t ws_size,
                              hipStream_t stream) {
  const float* emb      = (const float*)d_in[0];
  const float* emb_mask = (const float*)d_in[1];
  const float* enc      = (const float*)d_in[2];
  const float* enc_mask = (const float*)d_in[3];
  const int*   gt       = (const int*)d_in[4];
  const float* go       = (const float*)d_in[5];
  const float* W_ih     = (const float*)d_in[6];
  const float* W_hh     = (const float*)d_in[7];
  const float* b_ih     = (const float*)d_in[8];
  const float* b_hh     = (const float*)d_in[9];
  const float* W_dec    = (const float*)d_in[10];
  const float* b_dec    = (const float*)d_in[11];
  const float* W_feat   = (const float*)d_in[12];
  const float* b_feat   = (const float*)d_in[13];
  float* out = (float*)d_out;

  char* base = (char*)d_ws;
  size_t off = 0;
  auto take = [&](size_t bytes) {
    char* p = base + off;
    off += (bytes + 255) & ~(size_t)255;
    return p;
  };
  float* Xin   = (float*)take((size_t)TDEC * NB * DEMB * 4);
  float* XW    = (float*)take((size_t)TDEC * NB * G4 * 4);
  float* H     = (float*)take((size_t)TDEC * NB * DDEC * 4);
  float* decb  = (float*)take((size_t)TDEC * NB * DENC * 4);
  float* praw  = (float*)take((size_t)2 * NB * TDEC * 512 * 4);
  int*   ft    = (int*)  take((size_t)NB * NPTS * 4);
  unsigned* bar = (unsigned*)take(256);
  unsigned short* encT  = (unsigned short*)take((size_t)NB * DENC * 512 * 2);
  unsigned short* embB  = (unsigned short*)take((size_t)NB * NPTS * DEMB * 2);
  unsigned short* WfB   = (unsigned short*)take((size_t)513 * 2048 * 2);
  unsigned short* p_bf  = (unsigned short*)take((size_t)NB * TDEC * 512 * 2);
  unsigned short* HAcat = (unsigned short*)take((size_t)1600 * 2048 * 2);
  unsigned short* featb = (unsigned short*)take((size_t)1600 * 520 * 2);

  // prep
  k_zero<<<dim3(1), dim3(64), 0, stream>>>(bar);
  k_first<<<dim3((NB * NPTS + 255) / 256), dim3(256), 0, stream>>>(gt, ft);
  k_gather<<<dim3((TDEC * NB * DEMB + 255) / 256), dim3(256), 0, stream>>>(emb, gt, go, Xin);
  k_transposeEnc<<<dim3(8, 16, 32), dim3(256), 0, stream>>>(enc, encT);
  {
    int n8 = NB * NPTS * DEMB / 8;
    k_cvt8<<<dim3((n8 + 255) / 256), dim3(256), 0, stream>>>(emb, embB, n8);
  }
  {
    int n8 = 513 * 2048 / 8;
    k_cvt8<<<dim3((n8 + 255) / 256), dim3(256), 0, stream>>>(W_feat, WfB, n8);
  }

  GemmP q{};
  // XW = Xin @ W_ih^T + b_ih + b_hh   [1600 x 4096], K=512  (fp32)
  q.A = Xin; q.aBatch = 0; q.lda = DEMB;
  q.B = W_ih; q.bBatch = 0; q.ldb = DEMB;
  q.C = XW; q.cBatch = 0; q.ldcM = G4; q.ldcN = 1;
  q.M = TDEC * NB; q.N = G4; q.K = DEMB;
  q.bias1 = b_ih; q.bias2 = b_hh; q.kcN = 1; q.kcStride = 0;
  k_gemm<<<dim3(25, 64, 1), dim3(256), 0, stream>>>(q);

  // whole LSTM recurrence in one persistent kernel (50 steps, 50 grid barriers)
  k_lstm_persist<<<dim3(NBLK_LSTM), dim3(256), 0, stream>>>(W_hh, XW, H, bar);

  // dec = H @ W_dec^T + b_dec   [1600 x 1024], K=1024  (fp32)
  q = GemmP{};
  q.A = H; q.aBatch = 0; q.lda = DDEC;
  q.B = W_dec; q.bBatch = 0; q.ldb = DDEC;
  q.C = decb; q.cBatch = 0; q.ldcM = DENC; q.ldcN = 1;
  q.M = TDEC * NB; q.N = DENC; q.K = DDEC;
  q.bias1 = b_dec; q.bias2 = nullptr; q.kcN = 1; q.kcStride = 0;
  k_gemm<<<dim3(25, 16, 1), dim3(256), 0, stream>>>(q);

  // raw[b] = dec[b] @ enc[b]^T  [50 x 512], K=1024, split-K x2  (fp32)
  q = GemmP{};
  q.A = decb; q.aBatch = DENC; q.lda = NB * DENC;
  q.B = enc; q.bBatch = (long long)512 * DENC; q.ldb = DENC;
  q.C = praw; q.cBatch = (long long)TDEC * 512; q.ldcM = 512; q.ldcN = 1;
  q.M = TDEC; q.N = 512; q.K = DENC;
  q.bias1 = nullptr; q.bias2 = nullptr;
  q.kcN = 2; q.kcStride = (long long)NB * TDEC * 512;
  k_gemm<<<dim3(1, 8, 64), dim3(256), 0, stream>>>(q);

  // softmax (sums 2 chunks) -> bf16 p
  k_softmax<<<dim3(NB * TDEC), dim3(256), 0, stream>>>(praw, p_bf, enc_mask);

  // H -> HAcat[:, 0:1024] bf16
  k_cvtH<<<dim3((1600 * 128 + 255) / 256), dim3(256), 0, stream>>>(H, HAcat, 1600 * 128);

  GemmBP g{};
  // attn[b] = p[b] @ encT[b]^T  [50 x 1024], K=512 -> HAcat[:, 1024:2048]
  g.A = p_bf; g.aBatch = (long long)TDEC * 512; g.lda = 512;
  g.B = encT; g.bBatch = (long long)DENC * 512; g.ldb = 512;
  g.C = HAcat + 1024; g.cBatch = 2048; g.ldcM = (long long)NB * 2048; g.ldcN = 1;
  g.M = TDEC; g.N = DENC; g.K = 512;
  g.bias = nullptr; g.ft = nullptr; g.emb_mask = nullptr;
  k_bgemm<0><<<dim3(1, 16, 32), dim3(256), 0, stream>>>(g);

  // feat = HAcat @ W_feat^T + b_feat  [1600 x 513], K=2048 -> featb bf16 (ld 520)
  g = GemmBP{};
  g.A = HAcat; g.aBatch = 0; g.lda = 2048;
  g.B = WfB; g.bBatch = 0; g.ldb = 2048;
  g.C = featb; g.cBatch = 0; g.ldcM = 520; g.ldcN = 1;
  g.M = 1600; g.N = 513; g.K = 2048;
  g.bias = b_feat; g.ft = nullptr; g.emb_mask = nullptr;
  k_bgemm<0><<<dim3(25, 9, 1), dim3(256), 0, stream>>>(g);

  // score[b,t,n] = emb_bf[b] @ featb[b]^T + picked*fl - mask -> out
  g = GemmBP{};
  g.A = embB; g.aBatch = (long long)NPTS * DEMB; g.lda = DEMB;
  g.B = featb; g.bBatch = 520; g.ldb = NB * 520;
  g.C = out; g.cBatch = (long long)TDEC * NPTS; g.ldcM = 1; g.ldcN = NPTS;
  g.M = NPTS; g.N = TDEC; g.K = DEMB;
  g.bias = nullptr; g.ft = ft; g.emb_mask = emb_mask;
  k_bgemm<1><<<dim3(8, 1, 32), dim3(256), 0, stream>>>(g);
}

// Round 8
// 1535.952 us; speedup vs baseline: 1.9552x; 1.9552x over previous
//
#include <hip/hip_runtime.h>

// Problem constants
#define TDEC 50
#define NB   32
#define NPTS 512
#define DEMB 512
#define DENC 1024
#define DDEC 1024
#define G4   4096
#define NEGBIG 1e20f
#define NBLK_LSTM 512

__device__ __forceinline__ float sigf(float x) {
  float e = __expf(-fabsf(x));
  float r = 1.0f / (1.0f + e);
  return x >= 0.0f ? r : 1.0f - r;
}
__device__ __forceinline__ float tanh_(float x) {
  return 2.0f * sigf(2.0f * x) - 1.0f;
}
__device__ __forceinline__ unsigned short f2b(float f) {
  union { float f; unsigned int u; } v; v.f = f;
  unsigned int r = v.u + 0x7FFFu + ((v.u >> 16) & 1u);   // RNE
  return (unsigned short)(r >> 16);
}
__device__ __forceinline__ float b2f(unsigned short u) {
  union { unsigned int i; float f; } v; v.i = ((unsigned int)u) << 16;
  return v.f;
}

using bf16x8_t = __attribute__((ext_vector_type(8))) __bf16;
using u16x8    = __attribute__((ext_vector_type(8))) unsigned short;
using f32x4    = __attribute__((ext_vector_type(4))) float;

// ---------------- prep kernels ----------------

__global__ void k_zero(unsigned* __restrict__ flags) {
  flags[threadIdx.x] = 0u;   // 512 per-block arrival flags
}

__global__ void k_first(const int* __restrict__ gt, int* __restrict__ ft) {
  int idx = blockIdx.x * blockDim.x + threadIdx.x;
  if (idx >= NB * NPTS) return;
  int b = idx >> 9, n = idx & (NPTS - 1);
  int first = TDEC;
  for (int t = 0; t < TDEC; ++t) {
    int g = gt[b * TDEC + t];
    if (g == n && t < first) first = t;
  }
  ft[idx] = first;
}

__global__ void k_gather(const float* __restrict__ emb, const int* __restrict__ gt,
                         const float* __restrict__ go, float* __restrict__ Xin) {
  int idx = blockIdx.x * blockDim.x + threadIdx.x;
  if (idx >= TDEC * NB * DEMB) return;
  int d = idx & (DEMB - 1);
  int tb = idx >> 9;
  int b = tb & (NB - 1);
  int t = tb >> 5;
  float v;
  if (t == 0) v = go[d];
  else {
    int g = gt[b * TDEC + (t - 1)];
    v = emb[((long long)b * NPTS + g) * DEMB + d];
  }
  Xin[idx] = v;
}

// fp32 -> bf16 elementwise (n8 = count/8)
__global__ void k_cvt8(const float* __restrict__ s, unsigned short* __restrict__ d, int n8) {
  int idx = blockIdx.x * blockDim.x + threadIdx.x;
  if (idx >= n8) return;
  float4 a = *(const float4*)(s + (long long)idx * 8);
  float4 b = *(const float4*)(s + (long long)idx * 8 + 4);
  u16x8 o;
  o[0]=f2b(a.x); o[1]=f2b(a.y); o[2]=f2b(a.z); o[3]=f2b(a.w);
  o[4]=f2b(b.x); o[5]=f2b(b.y); o[6]=f2b(b.z); o[7]=f2b(b.w);
  *(u16x8*)(d + (long long)idx * 8) = o;
}

// H[r][1024] fp32 -> HAcat[r][0..1023] bf16 (row stride 2048)
__global__ void k_cvtH(const float* __restrict__ H, unsigned short* __restrict__ HAcat, int n8) {
  int idx = blockIdx.x * blockDim.x + threadIdx.x;
  if (idx >= n8) return;
  int r = idx >> 7, c = (idx & 127) << 3;
  float4 a = *(const float4*)(H + (long long)r * 1024 + c);
  float4 b = *(const float4*)(H + (long long)r * 1024 + c + 4);
  u16x8 o;
  o[0]=f2b(a.x); o[1]=f2b(a.y); o[2]=f2b(a.z); o[3]=f2b(a.w);
  o[4]=f2b(b.x); o[5]=f2b(b.y); o[6]=f2b(b.z); o[7]=f2b(b.w);
  *(u16x8*)(HAcat + (long long)r * 2048 + c) = o;
}

// enc[b][n][e] f32 -> encT[b][e][n] bf16
__global__ __launch_bounds__(256) void k_transposeEnc(const float* __restrict__ enc,
                                                      unsigned short* __restrict__ encT) {
  __shared__ float tile[64][65];
  int n0 = blockIdx.x * 64, e0 = blockIdx.y * 64, b = blockIdx.z;
  const float* E = enc + (long long)b * 512 * DENC;
  unsigned short* ET = encT + (long long)b * DENC * 512;
  int tid = threadIdx.x;
  int nr = tid >> 2, q = tid & 3;
#pragma unroll
  for (int i = 0; i < 4; ++i) {
    float4 v = *(const float4*)(E + (long long)(n0 + nr) * DENC + e0 + q * 16 + i * 4);
    tile[nr][q * 16 + i * 4 + 0] = v.x; tile[nr][q * 16 + i * 4 + 1] = v.y;
    tile[nr][q * 16 + i * 4 + 2] = v.z; tile[nr][q * 16 + i * 4 + 3] = v.w;
  }
  __syncthreads();
  int er = tid >> 2;
#pragma unroll
  for (int i = 0; i < 4; ++i) {
    ushort4 o;
    o.x = f2b(tile[q * 16 + i * 4 + 0][er]); o.y = f2b(tile[q * 16 + i * 4 + 1][er]);
    o.z = f2b(tile[q * 16 + i * 4 + 2][er]); o.w = f2b(tile[q * 16 + i * 4 + 3][er]);
    *(ushort4*)(ET + (long long)(e0 + er) * 512 + n0 + q * 16 + i * 4) = o;
  }
}

// ---------------- fp32 tiled GEMM (TN), with optional K-chunking ----------------
struct GemmP {
  const float* A; long long aBatch; int lda;
  const float* B; long long bBatch; int ldb;
  float* C; long long cBatch; long long ldcM; long long ldcN;
  int M, N, K;
  const float* bias1; const float* bias2;
  int kcN; long long kcStride;
};

__global__ __launch_bounds__(256) void k_gemm(GemmP p) {
  __shared__ float As[16][68];
  __shared__ float Bs[16][68];
  const int zb = blockIdx.z / p.kcN;
  const int kc = blockIdx.z % p.kcN;
  const float* A = p.A + (long long)zb * p.aBatch;
  const float* B = p.B + (long long)zb * p.bBatch;
  const int m0 = blockIdx.x * 64, n0 = blockIdx.y * 64;
  const int tid = threadIdx.x;
  const int lm = tid >> 2;
  const int lk = (tid & 3) << 2;
  const int tm = tid & 15, tn = tid >> 4;
  const int kChunk = p.K / p.kcN;
  const int kLo = kc * kChunk, kHi = kLo + kChunk;
  float acc[4][4] = {};
  for (int k0 = kLo; k0 < kHi; k0 += 16) {
    float4 av = make_float4(0.f, 0.f, 0.f, 0.f);
    float4 bv = make_float4(0.f, 0.f, 0.f, 0.f);
    {
      int am = m0 + lm, kk = k0 + lk;
      if (am < p.M) av = *(const float4*)(A + (long long)am * p.lda + kk);
    }
    {
      int bn = n0 + lm, kk = k0 + lk;
      if (bn < p.N) bv = *(const float4*)(B + (long long)bn * p.ldb + kk);
    }
    __syncthreads();
    As[lk + 0][lm] = av.x; As[lk + 1][lm] = av.y;
    As[lk + 2][lm] = av.z; As[lk + 3][lm] = av.w;
    Bs[lk + 0][lm] = bv.x; Bs[lk + 1][lm] = bv.y;
    Bs[lk + 2][lm] = bv.z; Bs[lk + 3][lm] = bv.w;
    __syncthreads();
#pragma unroll
    for (int kk = 0; kk < 16; ++kk) {
      float4 a = *(const float4*)&As[kk][tm << 2];
      float4 b = *(const float4*)&Bs[kk][tn << 2];
      float ar[4] = {a.x, a.y, a.z, a.w};
      float br[4] = {b.x, b.y, b.z, b.w};
#pragma unroll
      for (int i = 0; i < 4; ++i)
#pragma unroll
        for (int j = 0; j < 4; ++j) acc[i][j] += ar[i] * br[j];
    }
  }
  float* C = p.C + (long long)zb * p.cBatch + (long long)kc * p.kcStride;
#pragma unroll
  for (int i = 0; i < 4; ++i) {
    int m = m0 + (tm << 2) + i;
    if (m >= p.M) continue;
#pragma unroll
    for (int j = 0; j < 4; ++j) {
      int n = n0 + (tn << 2) + j;
      if (n >= p.N) continue;
      float v = acc[i][j];
      if (p.bias1) v += p.bias1[n];
      if (p.bias2) v += p.bias2[n];
      C[(long long)m * p.ldcM + (long long)n * p.ldcN] = v;
    }
  }
}

// ---------------- bf16 MFMA GEMM (TN: C = A * B^T), 64x64 tile, BK=32 ----------------
struct GemmBP {
  const unsigned short* A; long long aBatch; int lda;
  const unsigned short* B; long long bBatch; int ldb;
  void* C; long long cBatch; long long ldcM; long long ldcN;
  int M, N, K;
  const float* bias;
  const int* ft; const float* emb_mask;
};

template <int MODE>
__global__ __launch_bounds__(256) void k_bgemm(GemmBP p) {
  __shared__ unsigned short As[64][40];
  __shared__ unsigned short Bs[64][40];
  const int z = blockIdx.z;
  const unsigned short* A = p.A + (long long)z * p.aBatch;
  const unsigned short* B = p.B + (long long)z * p.bBatch;
  const int m0 = blockIdx.x * 64, n0 = blockIdx.y * 64;
  const int tid = threadIdx.x;
  const int srow = tid >> 2, skq = tid & 3;
  const int lane = tid & 63, wave = tid >> 6;
  const int wm = (wave >> 1) * 32, wn = (wave & 1) * 32;
  const int lr = lane & 15, lk = (lane >> 4) * 8;
  f32x4 acc[2][2] = {};
  for (int k0 = 0; k0 < p.K; k0 += 32) {
    u16x8 av = {}, bv = {};
    int gm = m0 + srow;
    if (gm < p.M) av = *(const u16x8*)(A + (long long)gm * p.lda + k0 + skq * 8);
    int gn = n0 + srow;
    if (gn < p.N) bv = *(const u16x8*)(B + (long long)gn * p.ldb + k0 + skq * 8);
    __syncthreads();
    *(u16x8*)&As[srow][skq * 8] = av;
    *(u16x8*)&Bs[srow][skq * 8] = bv;
    __syncthreads();
#pragma unroll
    for (int mi = 0; mi < 2; ++mi) {
      bf16x8_t af = *(const bf16x8_t*)&As[wm + mi * 16 + lr][lk];
#pragma unroll
      for (int ni = 0; ni < 2; ++ni) {
        bf16x8_t bfv = *(const bf16x8_t*)&Bs[wn + ni * 16 + lr][lk];
        acc[mi][ni] = __builtin_amdgcn_mfma_f32_16x16x32_bf16(af, bfv, acc[mi][ni], 0, 0, 0);
      }
    }
  }
  const int rbase = (lane >> 4) * 4, cOff = lane & 15;
#pragma unroll
  for (int mi = 0; mi < 2; ++mi)
#pragma unroll
    for (int ni = 0; ni < 2; ++ni)
#pragma unroll
      for (int r = 0; r < 4; ++r) {
        int m = m0 + wm + mi * 16 + rbase + r;
        int n = n0 + wn + ni * 16 + cOff;
        if (m >= p.M || n >= p.N) continue;
        float v = acc[mi][ni][r];
        if (MODE == 0) {
          if (p.bias) v += p.bias[n];
          ((unsigned short*)p.C)[(long long)z * p.cBatch + (long long)m * p.ldcM +
                                 (long long)n * p.ldcN] = f2b(v);
        } else {
          float fl = b2f(B[(long long)n * p.ldb + DEMB]);
          if (p.ft[z * NPTS + m] < n) v += fl;
          v -= (1.0f - p.emb_mask[z * NPTS + m]) * NEGBIG;
          ((float*)p.C)[(long long)z * p.cBatch + (long long)m * p.ldcM +
                        (long long)n * p.ldcN] = v;
        }
      }
}

// ---------------- persistent LSTM: one kernel, 50 steps, flag-array barrier ----------------
// 512 blocks x 256 threads (2 blocks/CU, co-resident — proven in round 7). Block bid owns
// hidden units {bid*2, bid*2+1} (8 W_hh rows staged once in LDS). Per step: matvec vs
// h_{t-1} (normal loads; lines are never cached by any XCD before their producing step's
// barrier, and kernel dispatch begins with cache invalidate, so they are always fresh),
// cell update, then:
//   publish: h values via relaxed AGENT atomic stores (write-through to coherence point),
//            wave-local s_waitcnt vmcnt(0), then flags[bid] = t+1 (relaxed AGENT store).
//   wait:    wave 0's 64 lanes poll all 512 flags in parallel (8 coalesced loads/lane).
// No atomic RMW, no __threadfence (no buffer_wbl2/inv storms) — that was 53 us/step in r7.
__global__ __launch_bounds__(256, 2) void k_lstm_persist(
    const float* __restrict__ W_hh, const float* __restrict__ XW,
    float* __restrict__ H, unsigned* __restrict__ flags) {
  __shared__ float Wl[8][1028];   // pad: (r*1028+k)%32 = (r*4+k)%32 -> conflict-free
  __shared__ float gbuf[8][33];
  __shared__ float cst[2][32];
  const int bid = blockIdx.x;
  const int tid = threadIdx.x;
  // stage 8 W_hh rows: r -> j = (r>>1)*1024 + bid*2 + (r&1)
  for (int i = tid; i < 8 * 256; i += 256) {
    int r = i >> 8, kq = (i & 255) << 2;
    int j = (r >> 1) * 1024 + bid * 2 + (r & 1);
    float4 v = *(const float4*)(W_hh + (long long)j * 1024 + kq);
    Wl[r][kq + 0] = v.x; Wl[r][kq + 1] = v.y; Wl[r][kq + 2] = v.z; Wl[r][kq + 3] = v.w;
  }
  const int r = tid & 7, b = tid >> 3;
  const int j = (r >> 1) * 1024 + bid * 2 + (r & 1);
  __syncthreads();
  for (int t = 0; t < TDEC; ++t) {
    float acc = 0.f;
    if (t > 0) {
      const float* hp = H + ((long long)(t - 1) * NB + b) * DDEC;
#pragma unroll 8
      for (int k = 0; k < DDEC; k += 4) {
        float4 h4 = *(const float4*)(hp + k);
        float4 w4 = *(const float4*)&Wl[r][k];
        acc += w4.x * h4.x + w4.y * h4.y + w4.z * h4.z + w4.w * h4.w;
      }
    }
    acc += XW[((long long)t * NB + b) * G4 + j];
    gbuf[r][b] = acc;
    __syncthreads();
    if (tid < 64) {              // wave 0: cell update + publish + barrier wait
      int ul = tid >> 5, bb = tid & 31;
      float gi = gbuf[0 + ul][bb], gf = gbuf[2 + ul][bb];
      float gg = gbuf[4 + ul][bb], go_ = gbuf[6 + ul][bb];
      float cp = (t == 0) ? 0.f : cst[ul][bb];
      float cv = sigf(gf) * cp + sigf(gi) * tanh_(gg);
      cst[ul][bb] = cv;
      float hv = sigf(go_) * tanh_(cv);
      // write-through h store (coherence point), one per lane
      __hip_atomic_store(&H[((long long)t * NB + bb) * DDEC + bid * 2 + ul], hv,
                         __ATOMIC_RELAXED, __HIP_MEMORY_SCOPE_AGENT);
      // all 64 lanes' stores retired at coherence point before flag publishes
      asm volatile("s_waitcnt vmcnt(0)" ::: "memory");
      if (tid == 0)
        __hip_atomic_store(&flags[bid], (unsigned)(t + 1),
                           __ATOMIC_RELAXED, __HIP_MEMORY_SCOPE_AGENT);
      if (t + 1 < TDEC) {
        const unsigned target = (unsigned)(t + 1);
        bool ok;
        do {
          ok = true;
#pragma unroll
          for (int i2 = 0; i2 < 8; ++i2) {
            unsigned f = __hip_atomic_load(&flags[tid + 64 * i2], __ATOMIC_RELAXED,
                                           __HIP_MEMORY_SCOPE_AGENT);
            ok = ok && (f >= target);
          }
        } while (!__all(ok));
      }
    }
    __syncthreads();
  }
}

// ---------------- masked softmax over 512, sums 2 K-chunks, emits bf16 p ----------------
__global__ __launch_bounds__(256) void k_softmax(const float* __restrict__ praw,
                                                 unsigned short* __restrict__ p_bf,
                                                 const float* __restrict__ enc_mask) {
  __shared__ float red[8];
  __shared__ float red2[8];
  const long long kcStride = (long long)NB * TDEC * 512;
  int bt = blockIdx.x;
  int b = bt / TDEC;
  const float* r0 = praw + (long long)bt * 512;
  const float* r1 = r0 + kcStride;
  int tid = threadIdx.x;
  float v0 = r0[tid] + r1[tid] - (1.0f - enc_mask[b * 512 + tid]) * NEGBIG;
  float v1 = r0[tid + 256] + r1[tid + 256] - (1.0f - enc_mask[b * 512 + tid + 256]) * NEGBIG;
  float mx = fmaxf(v0, v1);
  for (int off = 32; off; off >>= 1) mx = fmaxf(mx, __shfl_xor(mx, off));
  if ((tid & 63) == 0) red[tid >> 6] = mx;
  __syncthreads();
  mx = fmaxf(fmaxf(red[0], red[1]), fmaxf(red[2], red[3]));
  float e0 = __expf(v0 - mx), e1 = __expf(v1 - mx);
  float s = e0 + e1;
  for (int off = 32; off; off >>= 1) s += __shfl_xor(s, off);
  if ((tid & 63) == 0) red2[tid >> 6] = s;
  __syncthreads();
  s = red2[0] + red2[1] + red2[2] + red2[3];
  float inv = 1.0f / s;
  p_bf[(long long)bt * 512 + tid] = f2b(e0 * inv);
  p_bf[(long long)bt * 512 + tid + 256] = f2b(e1 * inv);
}

// ---------------- host launcher ----------------
extern "C" void kernel_launch(void* const* d_in, const int* in_sizes, int n_in,
                              void* d_out, int out_size, void* d_ws, size_t ws_size,
                              hipStream_t stream) {
  const float* emb      = (const float*)d_in[0];
  const float* emb_mask = (const float*)d_in[1];
  const float* enc      = (const float*)d_in[2];
  const float* enc_mask = (const float*)d_in[3];
  const int*   gt       = (const int*)d_in[4];
  const float* go       = (const float*)d_in[5];
  const float* W_ih     = (const float*)d_in[6];
  const float* W_hh     = (const float*)d_in[7];
  const float* b_ih     = (const float*)d_in[8];
  const float* b_hh     = (const float*)d_in[9];
  const float* W_dec    = (const float*)d_in[10];
  const float* b_dec    = (const float*)d_in[11];
  const float* W_feat   = (const float*)d_in[12];
  const float* b_feat   = (const float*)d_in[13];
  float* out = (float*)d_out;

  char* base = (char*)d_ws;
  size_t off = 0;
  auto take = [&](size_t bytes) {
    char* p = base + off;
    off += (bytes + 255) & ~(size_t)255;
    return p;
  };
  float* Xin   = (float*)take((size_t)TDEC * NB * DEMB * 4);
  float* XW    = (float*)take((size_t)TDEC * NB * G4 * 4);
  float* H     = (float*)take((size_t)TDEC * NB * DDEC * 4);
  float* decb  = (float*)take((size_t)TDEC * NB * DENC * 4);
  float* praw  = (float*)take((size_t)2 * NB * TDEC * 512 * 4);
  int*   ft    = (int*)  take((size_t)NB * NPTS * 4);
  unsigned* flags = (unsigned*)take((size_t)NBLK_LSTM * 4);
  unsigned short* encT  = (unsigned short*)take((size_t)NB * DENC * 512 * 2);
  unsigned short* embB  = (unsigned short*)take((size_t)NB * NPTS * DEMB * 2);
  unsigned short* WfB   = (unsigned short*)take((size_t)513 * 2048 * 2);
  unsigned short* p_bf  = (unsigned short*)take((size_t)NB * TDEC * 512 * 2);
  unsigned short* HAcat = (unsigned short*)take((size_t)1600 * 2048 * 2);
  unsigned short* featb = (unsigned short*)take((size_t)1600 * 520 * 2);

  // prep
  k_zero<<<dim3(1), dim3(NBLK_LSTM), 0, stream>>>(flags);
  k_first<<<dim3((NB * NPTS + 255) / 256), dim3(256), 0, stream>>>(gt, ft);
  k_gather<<<dim3((TDEC * NB * DEMB + 255) / 256), dim3(256), 0, stream>>>(emb, gt, go, Xin);
  k_transposeEnc<<<dim3(8, 16, 32), dim3(256), 0, stream>>>(enc, encT);
  {
    int n8 = NB * NPTS * DEMB / 8;
    k_cvt8<<<dim3((n8 + 255) / 256), dim3(256), 0, stream>>>(emb, embB, n8);
  }
  {
    int n8 = 513 * 2048 / 8;
    k_cvt8<<<dim3((n8 + 255) / 256), dim3(256), 0, stream>>>(W_feat, WfB, n8);
  }

  GemmP q{};
  // XW = Xin @ W_ih^T + b_ih + b_hh   [1600 x 4096], K=512  (fp32)
  q.A = Xin; q.aBatch = 0; q.lda = DEMB;
  q.B = W_ih; q.bBatch = 0; q.ldb = DEMB;
  q.C = XW; q.cBatch = 0; q.ldcM = G4; q.ldcN = 1;
  q.M = TDEC * NB; q.N = G4; q.K = DEMB;
  q.bias1 = b_ih; q.bias2 = b_hh; q.kcN = 1; q.kcStride = 0;
  k_gemm<<<dim3(25, 64, 1), dim3(256), 0, stream>>>(q);

  // whole LSTM recurrence in one persistent kernel (50 steps, flag-array barriers)
  k_lstm_persist<<<dim3(NBLK_LSTM), dim3(256), 0, stream>>>(W_hh, XW, H, flags);

  // dec = H @ W_dec^T + b_dec   [1600 x 1024], K=1024  (fp32)
  q = GemmP{};
  q.A = H; q.aBatch = 0; q.lda = DDEC;
  q.B = W_dec; q.bBatch = 0; q.ldb = DDEC;
  q.C = decb; q.cBatch = 0; q.ldcM = DENC; q.ldcN = 1;
  q.M = TDEC * NB; q.N = DENC; q.K = DDEC;
  q.bias1 = b_dec; q.bias2 = nullptr; q.kcN = 1; q.kcStride = 0;
  k_gemm<<<dim3(25, 16, 1), dim3(256), 0, stream>>>(q);

  // raw[b] = dec[b] @ enc[b]^T  [50 x 512], K=1024, split-K x2  (fp32)
  q = GemmP{};
  q.A = decb; q.aBatch = DENC; q.lda = NB * DENC;
  q.B = enc; q.bBatch = (long long)512 * DENC; q.ldb = DENC;
  q.C = praw; q.cBatch = (long long)TDEC * 512; q.ldcM = 512; q.ldcN = 1;
  q.M = TDEC; q.N = 512; q.K = DENC;
  q.bias1 = nullptr; q.bias2 = nullptr;
  q.kcN = 2; q.kcStride = (long long)NB * TDEC * 512;
  k_gemm<<<dim3(1, 8, 64), dim3(256), 0, stream>>>(q);

  // softmax (sums 2 chunks) -> bf16 p
  k_softmax<<<dim3(NB * TDEC), dim3(256), 0, stream>>>(praw, p_bf, enc_mask);

  // H -> HAcat[:, 0:1024] bf16
  k_cvtH<<<dim3((1600 * 128 + 255) / 256), dim3(256), 0, stream>>>(H, HAcat, 1600 * 128);

  GemmBP g{};
  // attn[b] = p[b] @ encT[b]^T  [50 x 1024], K=512 -> HAcat[:, 1024:2048]
  g.A = p_bf; g.aBatch = (long long)TDEC * 512; g.lda = 512;
  g.B = encT; g.bBatch = (long long)DENC * 512; g.ldb = 512;
  g.C = HAcat + 1024; g.cBatch = 2048; g.ldcM = (long long)NB * 2048; g.ldcN = 1;
  g.M = TDEC; g.N = DENC; g.K = 512;
  g.bias = nullptr; g.ft = nullptr; g.emb_mask = nullptr;
  k_bgemm<0><<<dim3(1, 16, 32), dim3(256), 0, stream>>>(g);

  // feat = HAcat @ W_feat^T + b_feat  [1600 x 513], K=2048 -> featb bf16 (ld 520)
  g = GemmBP{};
  g.A = HAcat; g.aBatch = 0; g.lda = 2048;
  g.B = WfB; g.bBatch = 0; g.ldb = 2048;
  g.C = featb; g.cBatch = 0; g.ldcM = 520; g.ldcN = 1;
  g.M = 1600; g.N = 513; g.K = 2048;
  g.bias = b_feat; g.ft = nullptr; g.emb_mask = nullptr;
  k_bgemm<0><<<dim3(25, 9, 1), dim3(256), 0, stream>>>(g);

  // score[b,t,n] = emb_bf[b] @ featb[b]^T + picked*fl - mask -> out
  g = GemmBP{};
  g.A = embB; g.aBatch = (long long)NPTS * DEMB; g.lda = DEMB;
  g.B = featb; g.bBatch = 520; g.ldb = NB * 520;
  g.C = out; g.cBatch = (long long)TDEC * NPTS; g.ldcM = 1; g.ldcN = NPTS;
  g.M = NPTS; g.N = TDEC; g.K = DEMB;
  g.bias = nullptr; g.ft = ft; g.emb_mask = emb_mask;
  k_bgemm<1><<<dim3(8, 1, 32), dim3(256), 0, stream>>>(g);
}